// Round 26
// baseline (444.598 us; speedup 1.0000x reference)
//
#include <hip/hip_runtime.h>
#include <cmath>

#define NB 800
#define BB 8
#define FF 12
#define DD 32
#define DIMM 40
#define KSEL 20
#define NN_ ((size_t)NB * NB)
#define NSEL (BB * NB * KSEL)
#define XK 384   // FF*DD

typedef _Float16 f16x8 __attribute__((ext_vector_type(8)));
typedef _Float16 f16x4 __attribute__((ext_vector_type(4)));
typedef float    f32x4 __attribute__((ext_vector_type(4)));

// two-step mul-add with contraction barrier: matches numpy's round(v + round(0.01*n))
__device__ __forceinline__ float score_f32(float v, float n) {
    float p = 0.01f * n;
    asm volatile("" : "+v"(p));
    return v + p;
}

#define REG_SCAN_13(rv, l, g, selIdx, SELW)                                   \
    for (int t = 0; t < KSEL; ++t) {                                          \
        float bv = -2.0e30f; int bi = NB;                                     \
        _Pragma("unroll")                                                     \
        for (int k = 0; k < 13; ++k) {                                        \
            int i_ = l + k * 64;                                              \
            float s_ = rv[k];                                                 \
            if (s_ > bv) { bv = s_; bi = i_; }                                \
        }                                                                     \
        _Pragma("unroll")                                                     \
        for (int m_ = 32; m_ >= 1; m_ >>= 1) {                                \
            float ov = __shfl_xor(bv, m_, 64);                                \
            int   oi = __shfl_xor(bi, m_, 64);                                \
            if (ov > bv || (ov == bv && oi < bi)) { bv = ov; bi = oi; }       \
        }                                                                     \
        _Pragma("unroll")                                                     \
        for (int k = 0; k < 13; ++k) {                                        \
            int i_ = l + k * 64;                                              \
            if (i_ == bi) rv[k] = -1.0e30f;                                   \
        }                                                                     \
        if (l == 0) { selIdx[g][t] = bi; SELW; }                              \
    }

// nT[m][i] = tanh(alpha*(emb_i . W_m + b_m)) for m<40; rows 40..63 zero (K-pad).
__global__ __launch_bounds__(256) void lin_tanh_t_kernel(
    const float* __restrict__ emb, const float* __restrict__ W,
    const float* __restrict__ bias, const float* __restrict__ alphaP,
    float* __restrict__ outT)
{
    int idx = blockIdx.x * 256 + threadIdx.x;
    if (idx >= NB * 64) return;
    int i = idx >> 6, m = idx & 63;
    float r = 0.f;
    if (m < DIMM) {
        float acc = 0.f;
        #pragma unroll
        for (int d = 0; d < DIMM; ++d) acc += emb[i * DIMM + d] * W[m * DIMM + d];
        acc += bias[m];
        r = tanhf(alphaP[0] * acc);
    }
    outT[(size_t)m * NB + i] = r;
}

// xnode f16 hi/lo: xn[b][n][f*32+d] = split(x[b][f][n][d])
__global__ __launch_bounds__(256) void xnode_kernel(
    const float* __restrict__ x, _Float16* __restrict__ xh,
    _Float16* __restrict__ xl)
{
    size_t idx = (size_t)blockIdx.x * 256 + threadIdx.x;
    if (idx >= (size_t)BB * FF * NB * DD) return;
    int d = idx & 31;
    size_t r = idx >> 5;
    int n = r % NB; r /= NB;
    int f = r % FF; int b = (int)(r / FF);
    float v = x[idx];
    _Float16 h = (_Float16)v;
    _Float16 lo = (_Float16)(v - (float)h);
    size_t o = ((size_t)b * NB + n) * XK + f * DD + d;
    xh[o] = h; xl[o] = lo;
}

// f32 -> f16 hi/lo split (flat array)
__global__ __launch_bounds__(256) void split_kernel(
    const float* __restrict__ src, _Float16* __restrict__ h,
    _Float16* __restrict__ l, int n)
{
    int i = blockIdx.x * 256 + threadIdx.x;
    if (i >= n) return;
    float v = src[i];
    _Float16 hh = (_Float16)v;
    h[i] = hh;
    l[i] = (_Float16)(v - (float)hh);
}

// transpose 800x800 f32 -> f16 hi/lo: dst[j][e] = split(src[e][j])
__global__ __launch_bounds__(256) void transpose_split_kernel(
    const float* __restrict__ src, _Float16* __restrict__ h,
    _Float16* __restrict__ l)
{
    __shared__ float T[32][33];
    int e0 = blockIdx.y * 32, j0 = blockIdx.x * 32;
    int tid = threadIdx.x;
    int r = tid >> 3, c4 = (tid & 7) * 4;
    float4 v = *(const float4*)(src + (size_t)(e0 + r) * NB + j0 + c4);
    T[r][c4 + 0] = v.x; T[r][c4 + 1] = v.y; T[r][c4 + 2] = v.z; T[r][c4 + 3] = v.w;
    __syncthreads();
    #pragma unroll
    for (int q = 0; q < 4; ++q) {
        float x = T[c4 + q][r];
        _Float16 hh = (_Float16)x;
        size_t o = (size_t)(j0 + r) * NB + e0 + c4 + q;
        h[o] = hh;
        l[o] = (_Float16)(x - (float)hh);
    }
}

// Gram via split-f16 MFMA, 64x64 tile/wave, TRIANGULAR 13x13 tiles (tj>=ti),
// 2 waves/block. Off-diag values + mirrors bit-identical to 32-tile version;
// diagonal-tile lower 32-subblocks computed directly (<=1ulp vs mirror).
// Edge tiles: OOB reads stay inside ws; stores guarded.
__global__ __launch_bounds__(128) void gram_mfma64_kernel(
    const _Float16* __restrict__ xh, const _Float16* __restrict__ xl,
    _Float16* __restrict__ vh, _Float16* __restrict__ vl)
{
    int bid = blockIdx.x;
    int bt = bid & 15;
    int t = (bid >> 4) * 2 + (threadIdx.x >> 6);
    if (t >= 91) return;
    int ti = 0, rem = t;
    while (rem >= 13 - ti) { rem -= 13 - ti; ++ti; }
    int tj = ti + rem;
    int i0 = ti * 64, j0 = tj * 64;
    int l = threadIdx.x & 63;
    int lr = l & 15, kb = l >> 4;
    const _Float16* XH = xh + (size_t)bt * NB * XK;
    const _Float16* XL = xl + (size_t)bt * NB * XK;
    f32x4 acc[4][4];
    #pragma unroll
    for (int mi = 0; mi < 4; ++mi)
        #pragma unroll
        for (int mj = 0; mj < 4; ++mj)
            acc[mi][mj] = (f32x4){0.f, 0.f, 0.f, 0.f};
    size_t aB[4], bB[4];
    #pragma unroll
    for (int f = 0; f < 4; ++f) {
        aB[f] = (size_t)(i0 + f * 16 + lr) * XK + kb * 8;
        bB[f] = (size_t)(j0 + f * 16 + lr) * XK + kb * 8;
    }
    for (int kt = 0; kt < XK; kt += 32) {
        f16x8 ah[4], al[4], bh[4], bl[4];
        #pragma unroll
        for (int f = 0; f < 4; ++f) {
            ah[f] = *(const f16x8*)(XH + aB[f] + kt);
            al[f] = *(const f16x8*)(XL + aB[f] + kt);
            bh[f] = *(const f16x8*)(XH + bB[f] + kt);
            bl[f] = *(const f16x8*)(XL + bB[f] + kt);
        }
        #pragma unroll
        for (int mi = 0; mi < 4; ++mi)
            #pragma unroll
            for (int mj = 0; mj < 4; ++mj) {
                acc[mi][mj] = __builtin_amdgcn_mfma_f32_16x16x32_f16(al[mi], bl[mj], acc[mi][mj], 0, 0, 0);
                acc[mi][mj] = __builtin_amdgcn_mfma_f32_16x16x32_f16(al[mi], bh[mj], acc[mi][mj], 0, 0, 0);
                acc[mi][mj] = __builtin_amdgcn_mfma_f32_16x16x32_f16(ah[mi], bl[mj], acc[mi][mj], 0, 0, 0);
                acc[mi][mj] = __builtin_amdgcn_mfma_f32_16x16x32_f16(ah[mi], bh[mj], acc[mi][mj], 0, 0, 0);
            }
    }
    _Float16* VH = vh + (size_t)bt * NN_;
    _Float16* VL = vl + (size_t)bt * NN_;
    bool mirror = (ti != tj);
    #pragma unroll
    for (int mi = 0; mi < 4; ++mi)
        #pragma unroll
        for (int mj = 0; mj < 4; ++mj) {
            f16x4 ph, pl;
            int j = j0 + mj * 16 + lr;
            int ib = i0 + mi * 16 + kb * 4;
            #pragma unroll
            for (int r = 0; r < 4; ++r) {
                int i = ib + r;
                float v = tanhf(acc[mi][mj][r] / 12.0f);
                _Float16 h = (_Float16)v;
                _Float16 lo = (_Float16)(v - (float)h);
                if (i < NB && j < NB) {
                    VH[(size_t)i * NB + j] = h;
                    VL[(size_t)i * NB + j] = lo;
                }
                ph[r] = h; pl[r] = lo;
            }
            if (mirror && j < NB && ib < NB) {
                *(f16x4*)(VH + (size_t)j * NB + ib) = ph;
                *(f16x4*)(VL + (size_t)j * NB + ib) = pl;
            }
        }
}

// M = v1 @ v2^T via split-f16 MFMA, 64x64 tile/wave (halved L2 traffic),
// 2 waves/block. Partial edge tiles: OOB rows read garbage (in-ws), stores
// guarded. Per-element accumulation chain identical to 32x32 -> bit-exact.
__global__ __launch_bounds__(128) void mfma_m64_kernel(
    const _Float16* __restrict__ vh, const _Float16* __restrict__ vl,
    float* __restrict__ M)
{
    int bid = blockIdx.x;
    int b = bid & 7;
    int t = (bid >> 3) * 2 + (threadIdx.x >> 6);
    if (t >= 169) return;
    int ti = t / 13, tj = t % 13;
    int i0 = ti * 64, j0 = tj * 64;
    int l = threadIdx.x & 63;
    int lr = l & 15, kb = l >> 4;
    const _Float16* AH = vh + (size_t)b * NN_;
    const _Float16* AL = vl + (size_t)b * NN_;
    const _Float16* BH = vh + (size_t)(8 + b) * NN_;
    const _Float16* BL = vl + (size_t)(8 + b) * NN_;
    f32x4 acc[4][4];
    #pragma unroll
    for (int mi = 0; mi < 4; ++mi)
        #pragma unroll
        for (int mj = 0; mj < 4; ++mj)
            acc[mi][mj] = (f32x4){0.f, 0.f, 0.f, 0.f};
    size_t aB[4], bB[4];
    #pragma unroll
    for (int f = 0; f < 4; ++f) {
        aB[f] = (size_t)(i0 + f * 16 + lr) * NB + kb * 8;
        bB[f] = (size_t)(j0 + f * 16 + lr) * NB + kb * 8;
    }
    for (int kt = 0; kt < NB; kt += 32) {
        f16x8 ah[4], al[4], bh[4], bl[4];
        #pragma unroll
        for (int f = 0; f < 4; ++f) {
            ah[f] = *(const f16x8*)(AH + aB[f] + kt);
            al[f] = *(const f16x8*)(AL + aB[f] + kt);
            bh[f] = *(const f16x8*)(BH + bB[f] + kt);
            bl[f] = *(const f16x8*)(BL + bB[f] + kt);
        }
        #pragma unroll
        for (int mi = 0; mi < 4; ++mi)
            #pragma unroll
            for (int mj = 0; mj < 4; ++mj) {
                acc[mi][mj] = __builtin_amdgcn_mfma_f32_16x16x32_f16(al[mi], bl[mj], acc[mi][mj], 0, 0, 0);
                acc[mi][mj] = __builtin_amdgcn_mfma_f32_16x16x32_f16(al[mi], bh[mj], acc[mi][mj], 0, 0, 0);
                acc[mi][mj] = __builtin_amdgcn_mfma_f32_16x16x32_f16(ah[mi], bl[mj], acc[mi][mj], 0, 0, 0);
                acc[mi][mj] = __builtin_amdgcn_mfma_f32_16x16x32_f16(ah[mi], bh[mj], acc[mi][mj], 0, 0, 0);
            }
    }
    float* Mb_ = M + (size_t)b * NN_;
    #pragma unroll
    for (int mi = 0; mi < 4; ++mi)
        #pragma unroll
        for (int mj = 0; mj < 4; ++mj)
            #pragma unroll
            for (int r = 0; r < 4; ++r) {
                int i = i0 + mi * 16 + kb * 4 + r;
                int j = j0 + mj * 16 + lr;
                if (i < NB && j < NB)
                    Mb_[(size_t)i * NB + j] = acc[mi][mj][r];
            }
}

// C[i][j] = sum_k A[i,k]*B[j,k] via split-f16 MFMA (r20/r21 prefetch form,
// K-step 32 with 1-deep register prefetch). Col-bias + NCOPY broadcast.
template<int NCOPY>
__global__ __launch_bounds__(256) void mfma_ab_kernel(
    const _Float16* __restrict__ Ah, const _Float16* __restrict__ Al,
    const _Float16* __restrict__ Bh, const _Float16* __restrict__ Bl,
    float* __restrict__ C, const float* __restrict__ bias, long copyStride)
{
    int t = blockIdx.x * 4 + (threadIdx.x >> 6);
    if (t >= 625) return;
    int ti = t / 25, tj = t % 25;
    int i0 = ti * 32, j0 = tj * 32;
    int l = threadIdx.x & 63;
    int lr = l & 15, kb = l >> 4;
    f32x4 acc[2][2];
    #pragma unroll
    for (int mi = 0; mi < 2; ++mi)
        #pragma unroll
        for (int mj = 0; mj < 2; ++mj)
            acc[mi][mj] = (f32x4){0.f, 0.f, 0.f, 0.f};
    size_t aBase0 = (size_t)(i0 + lr) * NB + kb * 8;
    size_t aBase1 = (size_t)(i0 + 16 + lr) * NB + kb * 8;
    size_t bBase0 = (size_t)(j0 + lr) * NB + kb * 8;
    size_t bBase1 = (size_t)(j0 + 16 + lr) * NB + kb * 8;
    f16x8 ah0 = *(const f16x8*)(Ah + aBase0), ah1 = *(const f16x8*)(Ah + aBase1);
    f16x8 al0 = *(const f16x8*)(Al + aBase0), al1 = *(const f16x8*)(Al + aBase1);
    f16x8 bh0 = *(const f16x8*)(Bh + bBase0), bh1 = *(const f16x8*)(Bh + bBase1);
    f16x8 bl0 = *(const f16x8*)(Bl + bBase0), bl1 = *(const f16x8*)(Bl + bBase1);
    for (int kt = 0; kt < NB; kt += 32) {
        f16x8 nah0, nah1, nal0, nal1, nbh0, nbh1, nbl0, nbl1;
        if (kt + 32 < NB) {
            size_t off = kt + 32;
            nah0 = *(const f16x8*)(Ah + aBase0 + off);
            nah1 = *(const f16x8*)(Ah + aBase1 + off);
            nal0 = *(const f16x8*)(Al + aBase0 + off);
            nal1 = *(const f16x8*)(Al + aBase1 + off);
            nbh0 = *(const f16x8*)(Bh + bBase0 + off);
            nbh1 = *(const f16x8*)(Bh + bBase1 + off);
            nbl0 = *(const f16x8*)(Bl + bBase0 + off);
            nbl1 = *(const f16x8*)(Bl + bBase1 + off);
        }
        f16x8 ahv[2] = {ah0, ah1}, alv[2] = {al0, al1};
        f16x8 bhv[2] = {bh0, bh1}, blv[2] = {bl0, bl1};
        #pragma unroll
        for (int mi = 0; mi < 2; ++mi)
            #pragma unroll
            for (int mj = 0; mj < 2; ++mj) {
                acc[mi][mj] = __builtin_amdgcn_mfma_f32_16x16x32_f16(alv[mi], blv[mj], acc[mi][mj], 0, 0, 0);
                acc[mi][mj] = __builtin_amdgcn_mfma_f32_16x16x32_f16(alv[mi], bhv[mj], acc[mi][mj], 0, 0, 0);
                acc[mi][mj] = __builtin_amdgcn_mfma_f32_16x16x32_f16(ahv[mi], blv[mj], acc[mi][mj], 0, 0, 0);
                acc[mi][mj] = __builtin_amdgcn_mfma_f32_16x16x32_f16(ahv[mi], bhv[mj], acc[mi][mj], 0, 0, 0);
            }
        ah0 = nah0; ah1 = nah1; al0 = nal0; al1 = nal1;
        bh0 = nbh0; bh1 = nbh1; bl0 = nbl0; bl1 = nbl1;
    }
    #pragma unroll
    for (int mi = 0; mi < 2; ++mi)
        #pragma unroll
        for (int mj = 0; mj < 2; ++mj)
            #pragma unroll
            for (int r = 0; r < 4; ++r) {
                int i = i0 + mi * 16 + kb * 4 + r;
                int j = j0 + mj * 16 + lr;
                float o = acc[mi][mj][r] + (bias ? bias[j] : 0.f);
                #pragma unroll
                for (int c = 0; c < NCOPY; ++c)
                    C[(size_t)c * copyStride + (size_t)i * NB + j] = o;
            }
}

// Generic 800x800 transpose: dst[j][e] = src[e][j].
__global__ __launch_bounds__(256) void transpose_kernel(
    const float* __restrict__ src, float* __restrict__ dst)
{
    __shared__ float T[32][33];
    int e0 = blockIdx.y * 32, j0 = blockIdx.x * 32;
    int tid = threadIdx.x;
    int r = tid >> 3, c4 = (tid & 7) * 4;
    float4 v = *(const float4*)(src + (size_t)(e0 + r) * NB + j0 + c4);
    T[r][c4 + 0] = v.x; T[r][c4 + 1] = v.y; T[r][c4 + 2] = v.z; T[r][c4 + 3] = v.w;
    __syncthreads();
    float4 o;
    o.x = T[c4 + 0][r]; o.y = T[c4 + 1][r]; o.z = T[c4 + 2][r]; o.w = T[c4 + 3][r];
    *(float4*)(dst + (size_t)(j0 + r) * NB + e0 + c4) = o;
}

// C[bz][i][j] = sum_k AT[bz][k][i] * BT[bz][k][j]  (k-major, 64x64, 4x4/thread).
template<int EPI>
__global__ __launch_bounds__(256) void gemm_kmaj64_kernel(
    const float* __restrict__ AT, const float* __restrict__ BT,
    float* __restrict__ C, int Kk,
    long aStride, long bStride, long cStride, int tilesX, int nBatch,
    const float* __restrict__ bias, int nCopies, long copyStride)
{
    int bid = blockIdx.x;
    int bz = bid % nBatch;
    int t_ = bid / nBatch;
    int i0 = (t_ / tilesX) * 64;
    int j0 = (t_ % tilesX) * 64;
    const float* Ab = AT + (size_t)bz * aStride;
    const float* Bb = BT + (size_t)bz * bStride;
    float* Cb = C + (size_t)bz * cStride;
    int tid = threadIdx.x;
    int tx = tid & 15, ty = tid >> 4;
    __shared__ __align__(16) float As[32][68];
    __shared__ __align__(16) float Bs[32][68];
    float acc[4][4] = {};
    for (int kt = 0; kt < Kk; kt += 32) {
        #pragma unroll
        for (int l = 0; l < 2; ++l) {
            int s = tid + l * 256;
            int k = s >> 4;
            int c4 = (s & 15) * 4;
            float4 va = make_float4(0.f, 0.f, 0.f, 0.f);
            if (i0 + c4 < NB) va = *(const float4*)(Ab + (size_t)(kt + k) * NB + i0 + c4);
            *(float4*)&As[k][c4] = va;
            float4 vb = make_float4(0.f, 0.f, 0.f, 0.f);
            if (j0 + c4 < NB) vb = *(const float4*)(Bb + (size_t)(kt + k) * NB + j0 + c4);
            *(float4*)&Bs[k][c4] = vb;
        }
        __syncthreads();
        #pragma unroll 8
        for (int kk = 0; kk < 32; ++kk) {
            float4 a4 = *(const float4*)&As[kk][ty * 4];
            float4 b4 = *(const float4*)&Bs[kk][tx * 4];
            acc[0][0] += a4.x * b4.x; acc[0][1] += a4.x * b4.y; acc[0][2] += a4.x * b4.z; acc[0][3] += a4.x * b4.w;
            acc[1][0] += a4.y * b4.x; acc[1][1] += a4.y * b4.y; acc[1][2] += a4.y * b4.z; acc[1][3] += a4.y * b4.w;
            acc[2][0] += a4.z * b4.x; acc[2][1] += a4.z * b4.y; acc[2][2] += a4.z * b4.z; acc[2][3] += a4.z * b4.w;
            acc[3][0] += a4.w * b4.x; acc[3][1] += a4.w * b4.y; acc[3][2] += a4.w * b4.z; acc[3][3] += a4.w * b4.w;
        }
        __syncthreads();
    }
    int j = j0 + tx * 4;
    if (j >= NB) return;
    #pragma unroll
    for (int m = 0; m < 4; ++m) {
        int i = i0 + ty * 4 + m;
        if (i >= NB) continue;
        float4 o;
        o.x = acc[m][0]; o.y = acc[m][1]; o.z = acc[m][2]; o.w = acc[m][3];
        *(float4*)(Cb + (size_t)i * NB + j) = o;
    }
}

// In-place antisymmetrization: M <- M - M^T per batch.
__global__ __launch_bounds__(256) void antisym_kernel(float* __restrict__ M, int nBatch)
{
    int bid = blockIdx.x;
    int b = bid % nBatch;
    int t_ = bid / nBatch;
    int ti = t_ / 25, tj = t_ % 25;
    if (ti > tj) return;
    float* Mb_ = M + (size_t)b * NN_;
    __shared__ float T1[32][33];
    __shared__ float T2[32][33];
    int tid = threadIdx.x;
    int r = tid >> 3, c4 = (tid & 7) * 4;
    int i0 = ti * 32, j0 = tj * 32;
    float4 x1 = *(const float4*)(Mb_ + (size_t)(i0 + r) * NB + j0 + c4);
    float4 x2 = *(const float4*)(Mb_ + (size_t)(j0 + r) * NB + i0 + c4);
    T1[r][c4] = x1.x; T1[r][c4 + 1] = x1.y; T1[r][c4 + 2] = x1.z; T1[r][c4 + 3] = x1.w;
    T2[r][c4] = x2.x; T2[r][c4 + 1] = x2.y; T2[r][c4 + 2] = x2.z; T2[r][c4 + 3] = x2.w;
    __syncthreads();
    float4 d1;
    d1.x = T1[r][c4 + 0] - T2[c4 + 0][r];
    d1.y = T1[r][c4 + 1] - T2[c4 + 1][r];
    d1.z = T1[r][c4 + 2] - T2[c4 + 2][r];
    d1.w = T1[r][c4 + 3] - T2[c4 + 3][r];
    *(float4*)(Mb_ + (size_t)(i0 + r) * NB + j0 + c4) = d1;
    if (ti != tj) {
        float4 d2;
        d2.x = T2[r][c4 + 0] - T1[c4 + 0][r];
        d2.y = T2[r][c4 + 1] - T1[c4 + 1][r];
        d2.z = T2[r][c4 + 2] - T1[c4 + 2][r];
        d2.w = T2[r][c4 + 3] - T1[c4 + 3][r];
        *(float4*)(Mb_ + (size_t)(j0 + r) * NB + i0 + c4) = d2;
    }
}

// Row top-K of D = S1 - S1^T: 4 rows/block, register-resident scan.
__global__ __launch_bounds__(256) void adj1_tile_kernel(
    const float* __restrict__ D, const float* __restrict__ alphaP,
    const float* __restrict__ noise, float* __restrict__ a1val, int* __restrict__ a1idx)
{
    int i0 = blockIdx.x * 4;
    int tid = threadIdx.x;
    __shared__ float sc[NB][5];
    __shared__ float vl[NB][5];
    __shared__ int selIdx[4][KSEL];
    float alpha = alphaP[0];
    if (tid < 200) {
        #pragma unroll
        for (int c = 0; c < 4; ++c) {
            int i = i0 + c;
            float4 d4 = *(const float4*)(D + (size_t)i * NB + tid * 4);
            float4 nz = *(const float4*)(noise + (size_t)i * NB + tid * 4);
            float4 th;
            th.x = tanhf(alpha * d4.x); th.y = tanhf(alpha * d4.y);
            th.z = tanhf(alpha * d4.z); th.w = tanhf(alpha * d4.w);
            th.x = th.x > 0.f ? th.x : 0.f;
            th.y = th.y > 0.f ? th.y : 0.f;
            th.z = th.z > 0.f ? th.z : 0.f;
            th.w = th.w > 0.f ? th.w : 0.f;
            int j = tid * 4;
            vl[j + 0][c] = th.x; vl[j + 1][c] = th.y; vl[j + 2][c] = th.z; vl[j + 3][c] = th.w;
            sc[j + 0][c] = score_f32(th.x, nz.x);
            sc[j + 1][c] = score_f32(th.y, nz.y);
            sc[j + 2][c] = score_f32(th.z, nz.z);
            sc[j + 3][c] = score_f32(th.w, nz.w);
        }
    }
    __syncthreads();
    int g = tid >> 6, l = tid & 63;
    float rv[13];
    #pragma unroll
    for (int k = 0; k < 13; ++k) {
        int i = l + k * 64;
        rv[k] = (i < NB) ? sc[i][g] : -3.0e30f;
    }
    REG_SCAN_13(rv, l, g, selIdx, ;)
    __syncthreads();
    if (tid < 4) {
        int tmp[KSEL];
        #pragma unroll
        for (int t = 0; t < KSEL; ++t) tmp[t] = selIdx[tid][t];
        for (int a = 1; a < KSEL; ++a) {
            int key = tmp[a]; int b = a - 1;
            while (b >= 0 && tmp[b] > key) { tmp[b + 1] = tmp[b]; --b; }
            tmp[b + 1] = key;
        }
        int i = i0 + tid;
        for (int t = 0; t < KSEL; ++t) {
            a1idx[i * KSEL + t] = tmp[t];
            a1val[i * KSEL + t] = vl[tmp[t]][tid];
        }
    }
}

// Column top-K of adj2, 4 columns/block, XCD-pinned, register-resident scan.
__global__ __launch_bounds__(256) void topk2_tile_kernel(
    const float* __restrict__ adj2, const float* __restrict__ noise,
    float* __restrict__ outp, int* __restrict__ sel2i, float* __restrict__ sel2v)
{
    int bid = blockIdx.x;
    int b = bid & 7;
    int j0 = (bid >> 3) * 4;
    int tid = threadIdx.x;
    const float* Ab = adj2 + (size_t)b * NN_;
    const float* Zb = noise + (size_t)b * NN_;
    float* Ob = outp + (size_t)b * NN_;
    __shared__ float sc[NB][5];
    __shared__ int selIdx[4][KSEL];
    float4 myval[4];
    #pragma unroll
    for (int k = 0; k < 4; ++k) {
        int i = tid + k * 256;
        if (i < NB) {
            float4 v  = *(const float4*)(Ab + (size_t)i * NB + j0);
            float4 nz = *(const float4*)(Zb + (size_t)i * NB + j0);
            myval[k] = v;
            sc[i][0] = score_f32(v.x, nz.x);
            sc[i][1] = score_f32(v.y, nz.y);
            sc[i][2] = score_f32(v.z, nz.z);
            sc[i][3] = score_f32(v.w, nz.w);
        }
    }
    __syncthreads();
    int g = tid >> 6, l = tid & 63;
    size_t lbase = ((size_t)b * NB + (j0 + g)) * KSEL;
    float rv[13];
    #pragma unroll
    for (int k = 0; k < 13; ++k) {
        int i = l + k * 64;
        rv[k] = (i < NB) ? sc[i][g] : -3.0e30f;
    }
    REG_SCAN_13(rv, l, g, selIdx, sel2i[lbase + t] = bi)
    if (l < KSEL) sc[selIdx[g][l]][g] = -1.0e30f;
    __syncthreads();
    #pragma unroll
    for (int k = 0; k < 4; ++k) {
        int i = tid + k * 256;
        if (i >= NB) continue;
        float vv[4] = {myval[k].x, myval[k].y, myval[k].z, myval[k].w};
        float o4[4];
        #pragma unroll
        for (int c = 0; c < 4; ++c) {
            bool seld = (sc[i][c] == -1.0e30f);
            o4[c] = seld ? vv[c] : 0.f;
            if (seld) {
                int rk = 0;
                for (int t = 0; t < KSEL; ++t) if (selIdx[c][t] == i) rk = t;
                sel2v[((size_t)b * NB + (j0 + c)) * KSEL + rk] = vv[c];
            }
        }
        *(float4*)(Ob + (size_t)i * NB + j0) = make_float4(o4[0], o4[1], o4[2], o4[3]);
    }
}

// Dense a3 values, row-streaming, XCD-pinned.
__global__ __launch_bounds__(256) void a3dense_kernel(
    const float* __restrict__ a2, const float* __restrict__ a1val,
    const int* __restrict__ a1idx, const float* __restrict__ alphaP,
    float* __restrict__ a3v)
{
    int bid = blockIdx.x;
    int b = bid & 7;
    int i = bid >> 3;
    int tid = threadIdx.x;
    __shared__ float sval[KSEL];
    __shared__ int   sidx[KSEL];
    if (tid < KSEL) { sval[tid] = a1val[i * KSEL + tid]; sidx[tid] = a1idx[i * KSEL + tid]; }
    __syncthreads();
    if (tid >= 200) return;
    float alpha = alphaP[0];
    const float* a2b = a2 + (size_t)b * NN_;
    int j = tid * 4;
    float4 acc = make_float4(0.f, 0.f, 0.f, 0.f);
    #pragma unroll
    for (int t = 0; t < KSEL; ++t) {
        float vt = sval[t];
        float4 s = *(const float4*)(a2b + (size_t)sidx[t] * NB + j);
        acc.x = fmaf(vt, s.x, acc.x);
        acc.y = fmaf(vt, s.y, acc.y);
        acc.z = fmaf(vt, s.z, acc.z);
        acc.w = fmaf(vt, s.w, acc.w);
    }
    float4 th;
    th.x = tanhf(alpha * acc.x); th.y = tanhf(alpha * acc.y);
    th.z = tanhf(alpha * acc.z); th.w = tanhf(alpha * acc.w);
    th.x = th.x > 0.f ? th.x : 0.f;
    th.y = th.y > 0.f ? th.y : 0.f;
    th.z = th.z > 0.f ? th.z : 0.f;
    th.w = th.w > 0.f ? th.w : 0.f;
    *(float4*)(a3v + (size_t)b * NN_ + (size_t)i * NB + j) = th;
}

// Column top-K of precomputed a3v, 4 columns/block, register-resident scan.
__global__ __launch_bounds__(256) void a3topk_tile_kernel(
    const float* __restrict__ a3v, const float* __restrict__ noise,
    int* __restrict__ sel3i, float* __restrict__ sel3v)
{
    int bid = blockIdx.x;
    int b = bid & 7;
    int j0 = (bid >> 3) * 4;
    int tid = threadIdx.x;
    const float* Ab = a3v + (size_t)b * NN_;
    const float* Zb = noise + (size_t)b * NN_;
    __shared__ float sc[NB][5];
    __shared__ int selIdx[4][KSEL];
    float4 myval[4];
    #pragma unroll
    for (int k = 0; k < 4; ++k) {
        int i = tid + k * 256;
        if (i < NB) {
            float4 v  = *(const float4*)(Ab + (size_t)i * NB + j0);
            float4 nz = *(const float4*)(Zb + (size_t)i * NB + j0);
            myval[k] = v;
            sc[i][0] = score_f32(v.x, nz.x);
            sc[i][1] = score_f32(v.y, nz.y);
            sc[i][2] = score_f32(v.z, nz.z);
            sc[i][3] = score_f32(v.w, nz.w);
        }
    }
    __syncthreads();
    int g = tid >> 6, l = tid & 63;
    size_t lbase = ((size_t)b * NB + (j0 + g)) * KSEL;
    float rv[13];
    #pragma unroll
    for (int k = 0; k < 13; ++k) {
        int i = l + k * 64;
        rv[k] = (i < NB) ? sc[i][g] : -3.0e30f;
    }
    REG_SCAN_13(rv, l, g, selIdx, sel3i[lbase + t] = bi)
    if (l < KSEL) sc[selIdx[g][l]][g] = -1.0e30f;
    __syncthreads();
    #pragma unroll
    for (int k = 0; k < 4; ++k) {
        int i = tid + k * 256;
        if (i >= NB) continue;
        float vv[4] = {myval[k].x, myval[k].y, myval[k].z, myval[k].w};
        #pragma unroll
        for (int c = 0; c < 4; ++c) {
            if (sc[i][c] == -1.0e30f) {
                int rk = 0;
                for (int t = 0; t < KSEL; ++t) if (selIdx[c][t] == i) rk = t;
                sel3v[((size_t)b * NB + (j0 + c)) * KSEL + rk] = vv[c];
            }
        }
    }
}

// Qn[i,:] = sum_t a1val[i,t]*Wqt[a1idx[i,t],:] + bq
__global__ __launch_bounds__(256) void qn_sparse_kernel(
    const float* __restrict__ a1v, const int* __restrict__ a1i,
    const float* __restrict__ Wqt, const float* __restrict__ bq,
    float* __restrict__ Qn)
{
    int i = blockIdx.x;
    int tid = threadIdx.x;
    __shared__ float sval[KSEL];
    __shared__ int   sidx[KSEL];
    if (tid < KSEL) { sval[tid] = a1v[i * KSEL + tid]; sidx[tid] = a1i[i * KSEL + tid]; }
    __syncthreads();
    for (int e = tid; e < NB; e += 256) {
        float acc = 0.f;
        #pragma unroll
        for (int t = 0; t < KSEL; ++t)
            acc = fmaf(sval[t], Wqt[(size_t)sidx[t] * NB + e], acc);
        Qn[(size_t)i * NB + e] = acc + bq[e];
    }
}

// scores[n,b] += a2val * g[n,j] over a2's selected entries
__global__ __launch_bounds__(256) void scatter_scores_kernel(
    const int* __restrict__ sel2i, const float* __restrict__ sel2v,
    const float* __restrict__ g, float* __restrict__ scores)
{
    int t = blockIdx.x * 256 + threadIdx.x;
    if (t >= NSEL) return;
    int j = (t / KSEL) % NB;
    int b = t / (KSEL * NB);
    int n = sel2i[t];
    float val = sel2v[t];
    atomicAdd(scores + (size_t)n * BB + b, val * g[(size_t)n * NB + j]);
}

// w[n,:] = softmax(scores[n,:]/sqrt(800))
__global__ __launch_bounds__(256) void softmax_w_kernel(
    const float* __restrict__ scores, float* __restrict__ w)
{
    int n = blockIdx.x * 256 + threadIdx.x;
    if (n >= NB) return;
    float s[BB];
    float mx = -INFINITY;
    for (int k = 0; k < BB; ++k) {
        s[k] = scores[(size_t)n * BB + k] / sqrtf(800.0f);
        if (s[k] > mx) mx = s[k];
    }
    float sum = 0.f;
    for (int k = 0; k < BB; ++k) { s[k] = expf(s[k] - mx); sum += s[k]; }
    for (int k = 0; k < BB; ++k) w[(size_t)n * BB + k] = s[k] / sum;
}

// u[n,j] += w[n,b] * a3val over a3's selected entries (row-major for MFMA A)
__global__ __launch_bounds__(256) void scatter_u_kernel(
    const int* __restrict__ sel3i, const float* __restrict__ sel3v,
    const float* __restrict__ w, float* __restrict__ u)
{
    int t = blockIdx.x * 256 + threadIdx.x;
    if (t >= NSEL) return;
    int j = (t / KSEL) % NB;
    int b = t / (KSEL * NB);
    int n = sel3i[t];
    float val = sel3v[t];
    atomicAdd(u + (size_t)n * NB + j, w[(size_t)n * BB + b] * val);
}

extern "C" void kernel_launch(void* const* d_in, const int* in_sizes, int n_in,
                              void* d_out, int out_size, void* d_ws, size_t ws_size,
                              hipStream_t stream)
{
    const float* tfeat      = (const float*)d_in[0];
    const float* dfeat      = (const float*)d_in[1];
    const float* alphaP     = (const float*)d_in[2];
    const float* emb1       = (const float*)d_in[3];
    const float* emb2       = (const float*)d_in[4];
    const float* lin1_w     = (const float*)d_in[5];
    const float* lin1_b     = (const float*)d_in[6];
    const float* lin2_w     = (const float*)d_in[7];
    const float* lin2_b     = (const float*)d_in[8];
    const float* in_proj_w  = (const float*)d_in[9];
    const float* in_proj_b  = (const float*)d_in[10];
    const float* out_proj_w = (const float*)d_in[11];
    const float* out_proj_b = (const float*)d_in[12];
    const float* noise1     = (const float*)d_in[13];
    const float* noise2     = (const float*)d_in[14];
    const float* noise3     = (const float*)d_in[15];
    float* out = (float*)d_out;

    const size_t NN  = NN_;               // 640000
    const size_t BNN = (size_t)BB * NN;   // 5120000

    float* ws  = (float*)d_ws;
    float* regA = ws;             // BNN f32: vh (16*NN f16); later u (f32)
    float* regB = regA + BNN;     // BNN f32: vl (16*NN f16); later g
    float* Mb  = regB + BNN;      // BNN f32: xnode hi/lo; M/adj2/a3v; Wqt + f16 pairs
    float* Qn  = Mb + BNN;        // NN  (S1 early, Qn later)
    float* Ob  = Qn + NN;         // NN  (n1T/n2T early, O later)
    float* a1v = Ob + NN;         // 16000
    int*   a1i = (int*)(a1v + NB * KSEL);       // 16000
    float* sel2v = (float*)(a1i + NB * KSEL);   // 128000
    int*   sel2i = (int*)(sel2v + NSEL);        // 128000
    float* sel3v = (float*)(sel2i + NSEL);      // 128000
    int*   sel3i = (int*)(sel3v + NSEL);        // 128000
    float* scores = (float*)(sel3i + NSEL);     // 6400
    float* wgt    = scores + NB * BB;           // 6400

    _Float16* vh = (_Float16*)regA;   // 16*NN f16
    _Float16* vl = (_Float16*)regB;   // 16*NN f16
    _Float16* xnh = (_Float16*)Mb;                 // 16*800*384 f16
    _Float16* xnl = xnh + (size_t)16 * NB * XK;    // 16*800*384 f16
    float* u   = regA;            // f32 after vh dead
    float* g   = regB;            // f32 after vl dead
    float* S1  = Qn;
    float* n1T = Ob;
    float* n2T = Ob + 64 * NB;
    float* a3v = Mb;              // adj2 dead after topk2
    float* Wqt = Mb;
    _Float16* f16b = (_Float16*)(Mb + NN);
    _Float16* Qh    = f16b;
    _Float16* Ql    = f16b + 1 * NN;
    _Float16* WkTh  = f16b + 2 * NN;
    _Float16* WkTl  = f16b + 3 * NN;
    _Float16* Wvh   = f16b + 4 * NN;
    _Float16* Wvl   = f16b + 5 * NN;
    _Float16* Wouth = f16b + 6 * NN;
    _Float16* Woutl = f16b + 7 * NN;
    _Float16* uh    = f16b + 8 * NN;
    _Float16* ul    = f16b + 9 * NN;
    _Float16* Oh    = f16b + 10 * NN;
    _Float16* Ol    = f16b + 11 * NN;
    float* OT = Ob;
    float* a2 = out;

    const float* bq = in_proj_b;
    const float* bv = in_proj_b + 2 * NB;
    const size_t XE = (size_t)BB * FF * NB * DD;

    // ---- adj1 path: S1 = n1 @ n2^T via k-major f32 gemm (bit-mimicking) ----
    lin_tanh_t_kernel<<<(NB * 64 + 255) / 256, 256, 0, stream>>>(emb1, lin1_w, lin1_b, alphaP, n1T);
    lin_tanh_t_kernel<<<(NB * 64 + 255) / 256, 256, 0, stream>>>(emb2, lin2_w, lin2_b, alphaP, n2T);
    gemm_kmaj64_kernel<0><<<13 * 13, 256, 0, stream>>>(n1T, n2T, S1, 64, 0, 0, 0, 13, 1, nullptr, 1, 0);
    antisym_kernel<<<25 * 25, 256, 0, stream>>>(S1, 1);
    adj1_tile_kernel<<<NB / 4, 256, 0, stream>>>(S1, alphaP, noise1, a1v, a1i);
    // ---- gram path: xnode f16 hi/lo -> triangular 64x64 MFMA gram ----
    xnode_kernel<<<(int)((XE + 255) / 256), 256, 0, stream>>>(tfeat, xnh, xnl);
    xnode_kernel<<<(int)((XE + 255) / 256), 256, 0, stream>>>(
        dfeat, xnh + (size_t)BB * NB * XK, xnl + (size_t)BB * NB * XK);
    gram_mfma64_kernel<<<16 * 46, 128, 0, stream>>>(xnh, xnl, vh, vl);
    // ---- M = v1 @ v2^T via 64x64 split-f16 MFMA (xnode dead), antisym, topk2 ----
    mfma_m64_kernel<<<8 * 85, 128, 0, stream>>>(vh, vl, Mb);
    antisym_kernel<<<25 * 25 * BB, 256, 0, stream>>>(Mb, BB);
    topk2_tile_kernel<<<(NB / 4) * BB, 256, 0, stream>>>(Mb, noise2, a2, sel2i, sel2v);
    a3dense_kernel<<<NB * BB, 256, 0, stream>>>(a2, a1v, a1i, alphaP, a3v);
    a3topk_tile_kernel<<<(NB / 4) * BB, 256, 0, stream>>>(a3v, noise3, sel3i, sel3v);
    // ---- attention fold: all dense GEMMs via split-f16 MFMA ----
    transpose_kernel<<<dim3(25, 25), 256, 0, stream>>>(in_proj_w, Wqt);          // Wq^T f32
    qn_sparse_kernel<<<NB, 256, 0, stream>>>(a1v, a1i, Wqt, bq, Qn);
    split_kernel<<<(int)((NN + 255) / 256), 256, 0, stream>>>(Qn, Qh, Ql, (int)NN);
    transpose_split_kernel<<<dim3(25, 25), 256, 0, stream>>>(in_proj_w + NN, WkTh, WkTl);
    mfma_ab_kernel<1><<<157, 256, 0, stream>>>(Qh, Ql, WkTh, WkTl, g, nullptr, 0);
    hipMemsetAsync(scores, 0, NB * BB * sizeof(float), stream);
    scatter_scores_kernel<<<NSEL / 256, 256, 0, stream>>>(sel2i, sel2v, g, scores);
    softmax_w_kernel<<<(NB + 255) / 256, 256, 0, stream>>>(scores, wgt);
    hipMemsetAsync(u, 0, NN * sizeof(float), stream);
    scatter_u_kernel<<<NSEL / 256, 256, 0, stream>>>(sel3i, sel3v, wgt, u);
    split_kernel<<<(int)((NN + 255) / 256), 256, 0, stream>>>(u, uh, ul, (int)NN);
    split_kernel<<<(int)((NN + 255) / 256), 256, 0, stream>>>(in_proj_w + 2 * NN, Wvh, Wvl, (int)NN);
    mfma_ab_kernel<1><<<157, 256, 0, stream>>>(uh, ul, Wvh, Wvl, OT, bv, 0);
    split_kernel<<<(int)((NN + 255) / 256), 256, 0, stream>>>(OT, Oh, Ol, (int)NN);
    split_kernel<<<(int)((NN + 255) / 256), 256, 0, stream>>>(out_proj_w, Wouth, Woutl, (int)NN);
    mfma_ab_kernel<8><<<157, 256, 0, stream>>>(Oh, Ol, Wouth, Woutl, out, out_proj_b, (long)NN);
}

// Round 27
// 428.999 us; speedup vs baseline: 1.0364x; 1.0364x over previous
//
#include <hip/hip_runtime.h>
#include <cmath>

#define NB 800
#define BB 8
#define FF 12
#define DD 32
#define DIMM 40
#define KSEL 20
#define NN_ ((size_t)NB * NB)
#define NSEL (BB * NB * KSEL)
#define XK 384   // FF*DD

typedef _Float16 f16x8 __attribute__((ext_vector_type(8)));
typedef _Float16 f16x4 __attribute__((ext_vector_type(4)));
typedef float    f32x4 __attribute__((ext_vector_type(4)));

// two-step mul-add with contraction barrier: matches numpy's round(v + round(0.01*n))
__device__ __forceinline__ float score_f32(float v, float n) {
    float p = 0.01f * n;
    asm volatile("" : "+v"(p));
    return v + p;
}

#define REG_SCAN_13(rv, l, g, selIdx, SELW)                                   \
    for (int t = 0; t < KSEL; ++t) {                                          \
        float bv = -2.0e30f; int bi = NB;                                     \
        _Pragma("unroll")                                                     \
        for (int k = 0; k < 13; ++k) {                                        \
            int i_ = l + k * 64;                                              \
            float s_ = rv[k];                                                 \
            if (s_ > bv) { bv = s_; bi = i_; }                                \
        }                                                                     \
        _Pragma("unroll")                                                     \
        for (int m_ = 32; m_ >= 1; m_ >>= 1) {                                \
            float ov = __shfl_xor(bv, m_, 64);                                \
            int   oi = __shfl_xor(bi, m_, 64);                                \
            if (ov > bv || (ov == bv && oi < bi)) { bv = ov; bi = oi; }       \
        }                                                                     \
        _Pragma("unroll")                                                     \
        for (int k = 0; k < 13; ++k) {                                        \
            int i_ = l + k * 64;                                              \
            if (i_ == bi) rv[k] = -1.0e30f;                                   \
        }                                                                     \
        if (l == 0) { selIdx[g][t] = bi; SELW; }                              \
    }

// One 32-k chunk of split-f16 4-product MFMAs into acc[2][2].
#define MFMA_CHUNK(acc, AH_, AL_, BH_, BL_, a0, a1, b0, b1, off)              \
    {                                                                         \
        f16x8 ah_[2] = { *(const f16x8*)(AH_ + a0 + (off)),                   \
                         *(const f16x8*)(AH_ + a1 + (off)) };                 \
        f16x8 al_[2] = { *(const f16x8*)(AL_ + a0 + (off)),                   \
                         *(const f16x8*)(AL_ + a1 + (off)) };                 \
        f16x8 bh_[2] = { *(const f16x8*)(BH_ + b0 + (off)),                   \
                         *(const f16x8*)(BH_ + b1 + (off)) };                 \
        f16x8 bl_[2] = { *(const f16x8*)(BL_ + b0 + (off)),                   \
                         *(const f16x8*)(BL_ + b1 + (off)) };                 \
        _Pragma("unroll")                                                     \
        for (int mi = 0; mi < 2; ++mi)                                        \
            _Pragma("unroll")                                                 \
            for (int mj = 0; mj < 2; ++mj) {                                  \
                acc[mi][mj] = __builtin_amdgcn_mfma_f32_16x16x32_f16(al_[mi], bl_[mj], acc[mi][mj], 0, 0, 0); \
                acc[mi][mj] = __builtin_amdgcn_mfma_f32_16x16x32_f16(al_[mi], bh_[mj], acc[mi][mj], 0, 0, 0); \
                acc[mi][mj] = __builtin_amdgcn_mfma_f32_16x16x32_f16(ah_[mi], bl_[mj], acc[mi][mj], 0, 0, 0); \
                acc[mi][mj] = __builtin_amdgcn_mfma_f32_16x16x32_f16(ah_[mi], bh_[mj], acc[mi][mj], 0, 0, 0); \
            }                                                                 \
    }

// nT[m][i] = tanh(alpha*(emb_i . W_m + b_m)) for m<40; rows 40..63 zero (K-pad).
__global__ __launch_bounds__(256) void lin_tanh_t_kernel(
    const float* __restrict__ emb, const float* __restrict__ W,
    const float* __restrict__ bias, const float* __restrict__ alphaP,
    float* __restrict__ outT)
{
    int idx = blockIdx.x * 256 + threadIdx.x;
    if (idx >= NB * 64) return;
    int i = idx >> 6, m = idx & 63;
    float r = 0.f;
    if (m < DIMM) {
        float acc = 0.f;
        #pragma unroll
        for (int d = 0; d < DIMM; ++d) acc += emb[i * DIMM + d] * W[m * DIMM + d];
        acc += bias[m];
        r = tanhf(alphaP[0] * acc);
    }
    outT[(size_t)m * NB + i] = r;
}

// xnode f16 hi/lo: xn[b][n][f*32+d] = split(x[b][f][n][d])
__global__ __launch_bounds__(256) void xnode_kernel(
    const float* __restrict__ x, _Float16* __restrict__ xh,
    _Float16* __restrict__ xl)
{
    size_t idx = (size_t)blockIdx.x * 256 + threadIdx.x;
    if (idx >= (size_t)BB * FF * NB * DD) return;
    int d = idx & 31;
    size_t r = idx >> 5;
    int n = r % NB; r /= NB;
    int f = r % FF; int b = (int)(r / FF);
    float v = x[idx];
    _Float16 h = (_Float16)v;
    _Float16 lo = (_Float16)(v - (float)h);
    size_t o = ((size_t)b * NB + n) * XK + f * DD + d;
    xh[o] = h; xl[o] = lo;
}

// f32 -> f16 hi/lo split (flat array)
__global__ __launch_bounds__(256) void split_kernel(
    const float* __restrict__ src, _Float16* __restrict__ h,
    _Float16* __restrict__ l, int n)
{
    int i = blockIdx.x * 256 + threadIdx.x;
    if (i >= n) return;
    float v = src[i];
    _Float16 hh = (_Float16)v;
    h[i] = hh;
    l[i] = (_Float16)(v - (float)hh);
}

// transpose 800x800 f32 -> f16 hi/lo: dst[j][e] = split(src[e][j])
__global__ __launch_bounds__(256) void transpose_split_kernel(
    const float* __restrict__ src, _Float16* __restrict__ h,
    _Float16* __restrict__ l)
{
    __shared__ float T[32][33];
    int e0 = blockIdx.y * 32, j0 = blockIdx.x * 32;
    int tid = threadIdx.x;
    int r = tid >> 3, c4 = (tid & 7) * 4;
    float4 v = *(const float4*)(src + (size_t)(e0 + r) * NB + j0 + c4);
    T[r][c4 + 0] = v.x; T[r][c4 + 1] = v.y; T[r][c4 + 2] = v.z; T[r][c4 + 3] = v.w;
    __syncthreads();
    #pragma unroll
    for (int q = 0; q < 4; ++q) {
        float x = T[c4 + q][r];
        _Float16 hh = (_Float16)x;
        size_t o = (size_t)(j0 + r) * NB + e0 + c4 + q;
        h[o] = hh;
        l[o] = (_Float16)(x - (float)hh);
    }
}

// Gram via split-f16 MFMA (4 products), 32x32 tile/wave, TRIANGULAR tiles
// (tj>=ti), K-step 64, bit-exact packed mirror-write. No LDS.
__global__ __launch_bounds__(256) void gram_mfma_kernel(
    const _Float16* __restrict__ xh, const _Float16* __restrict__ xl,
    _Float16* __restrict__ vh, _Float16* __restrict__ vl)
{
    int bid = blockIdx.x;
    int bt = bid & 15;
    int t = (bid >> 4) * 4 + (threadIdx.x >> 6);
    if (t >= 325) return;
    int ti = 0, rem = t;
    while (rem >= 25 - ti) { rem -= 25 - ti; ++ti; }
    int tj = ti + rem;
    int i0 = ti * 32, j0 = tj * 32;
    int l = threadIdx.x & 63;
    int lr = l & 15, kb = l >> 4;
    const _Float16* XH = xh + (size_t)bt * NB * XK;
    const _Float16* XL = xl + (size_t)bt * NB * XK;
    f32x4 acc[2][2];
    #pragma unroll
    for (int mi = 0; mi < 2; ++mi)
        #pragma unroll
        for (int mj = 0; mj < 2; ++mj)
            acc[mi][mj] = (f32x4){0.f, 0.f, 0.f, 0.f};
    size_t aBase0 = (size_t)(i0 + lr) * XK + kb * 8;
    size_t aBase1 = (size_t)(i0 + 16 + lr) * XK + kb * 8;
    size_t bBase0 = (size_t)(j0 + lr) * XK + kb * 8;
    size_t bBase1 = (size_t)(j0 + 16 + lr) * XK + kb * 8;
    for (int kt = 0; kt < XK; kt += 64) {
        MFMA_CHUNK(acc, XH, XL, XH, XL, aBase0, aBase1, bBase0, bBase1, kt)
        MFMA_CHUNK(acc, XH, XL, XH, XL, aBase0, aBase1, bBase0, bBase1, kt + 32)
    }
    _Float16* VH = vh + (size_t)bt * NN_;
    _Float16* VL = vl + (size_t)bt * NN_;
    bool mirror = (ti != tj);
    #pragma unroll
    for (int mi = 0; mi < 2; ++mi)
        #pragma unroll
        for (int mj = 0; mj < 2; ++mj) {
            f16x4 ph, pl;
            int j = j0 + mj * 16 + lr;
            #pragma unroll
            for (int r = 0; r < 4; ++r) {
                int i = i0 + mi * 16 + kb * 4 + r;
                float v = tanhf(acc[mi][mj][r] / 12.0f);
                _Float16 h = (_Float16)v;
                _Float16 lo = (_Float16)(v - (float)h);
                VH[(size_t)i * NB + j] = h;
                VL[(size_t)i * NB + j] = lo;
                ph[r] = h; pl[r] = lo;
            }
            if (mirror) {
                int ib = i0 + mi * 16 + kb * 4;
                *(f16x4*)(VH + (size_t)j * NB + ib) = ph;
                *(f16x4*)(VL + (size_t)j * NB + ib) = pl;
            }
        }
}

// M = v1 @ v2^T via split-f16 MFMA, 64x64 tile/wave (halved L2 traffic),
// 2 waves/block. Partial edge tiles: OOB rows read garbage (in-ws), stores
// guarded. Per-element accumulation chain identical to 32x32 -> bit-exact.
__global__ __launch_bounds__(128) void mfma_m64_kernel(
    const _Float16* __restrict__ vh, const _Float16* __restrict__ vl,
    float* __restrict__ M)
{
    int bid = blockIdx.x;
    int b = bid & 7;
    int t = (bid >> 3) * 2 + (threadIdx.x >> 6);
    if (t >= 169) return;
    int ti = t / 13, tj = t % 13;
    int i0 = ti * 64, j0 = tj * 64;
    int l = threadIdx.x & 63;
    int lr = l & 15, kb = l >> 4;
    const _Float16* AH = vh + (size_t)b * NN_;
    const _Float16* AL = vl + (size_t)b * NN_;
    const _Float16* BH = vh + (size_t)(8 + b) * NN_;
    const _Float16* BL = vl + (size_t)(8 + b) * NN_;
    f32x4 acc[4][4];
    #pragma unroll
    for (int mi = 0; mi < 4; ++mi)
        #pragma unroll
        for (int mj = 0; mj < 4; ++mj)
            acc[mi][mj] = (f32x4){0.f, 0.f, 0.f, 0.f};
    size_t aB[4], bB[4];
    #pragma unroll
    for (int f = 0; f < 4; ++f) {
        aB[f] = (size_t)(i0 + f * 16 + lr) * NB + kb * 8;
        bB[f] = (size_t)(j0 + f * 16 + lr) * NB + kb * 8;
    }
    for (int kt = 0; kt < NB; kt += 32) {
        f16x8 ah[4], al[4], bh[4], bl[4];
        #pragma unroll
        for (int f = 0; f < 4; ++f) {
            ah[f] = *(const f16x8*)(AH + aB[f] + kt);
            al[f] = *(const f16x8*)(AL + aB[f] + kt);
            bh[f] = *(const f16x8*)(BH + bB[f] + kt);
            bl[f] = *(const f16x8*)(BL + bB[f] + kt);
        }
        #pragma unroll
        for (int mi = 0; mi < 4; ++mi)
            #pragma unroll
            for (int mj = 0; mj < 4; ++mj) {
                acc[mi][mj] = __builtin_amdgcn_mfma_f32_16x16x32_f16(al[mi], bl[mj], acc[mi][mj], 0, 0, 0);
                acc[mi][mj] = __builtin_amdgcn_mfma_f32_16x16x32_f16(al[mi], bh[mj], acc[mi][mj], 0, 0, 0);
                acc[mi][mj] = __builtin_amdgcn_mfma_f32_16x16x32_f16(ah[mi], bl[mj], acc[mi][mj], 0, 0, 0);
                acc[mi][mj] = __builtin_amdgcn_mfma_f32_16x16x32_f16(ah[mi], bh[mj], acc[mi][mj], 0, 0, 0);
            }
    }
    float* Mb_ = M + (size_t)b * NN_;
    #pragma unroll
    for (int mi = 0; mi < 4; ++mi)
        #pragma unroll
        for (int mj = 0; mj < 4; ++mj)
            #pragma unroll
            for (int r = 0; r < 4; ++r) {
                int i = i0 + mi * 16 + kb * 4 + r;
                int j = j0 + mj * 16 + lr;
                if (i < NB && j < NB)
                    Mb_[(size_t)i * NB + j] = acc[mi][mj][r];
            }
}

// C[i][j] = sum_k A[i,k]*B[j,k] via split-f16 MFMA (r20/r21 prefetch form,
// K-step 32 with 1-deep register prefetch). Col-bias + NCOPY broadcast.
template<int NCOPY>
__global__ __launch_bounds__(256) void mfma_ab_kernel(
    const _Float16* __restrict__ Ah, const _Float16* __restrict__ Al,
    const _Float16* __restrict__ Bh, const _Float16* __restrict__ Bl,
    float* __restrict__ C, const float* __restrict__ bias, long copyStride)
{
    int t = blockIdx.x * 4 + (threadIdx.x >> 6);
    if (t >= 625) return;
    int ti = t / 25, tj = t % 25;
    int i0 = ti * 32, j0 = tj * 32;
    int l = threadIdx.x & 63;
    int lr = l & 15, kb = l >> 4;
    f32x4 acc[2][2];
    #pragma unroll
    for (int mi = 0; mi < 2; ++mi)
        #pragma unroll
        for (int mj = 0; mj < 2; ++mj)
            acc[mi][mj] = (f32x4){0.f, 0.f, 0.f, 0.f};
    size_t aBase0 = (size_t)(i0 + lr) * NB + kb * 8;
    size_t aBase1 = (size_t)(i0 + 16 + lr) * NB + kb * 8;
    size_t bBase0 = (size_t)(j0 + lr) * NB + kb * 8;
    size_t bBase1 = (size_t)(j0 + 16 + lr) * NB + kb * 8;
    f16x8 ah0 = *(const f16x8*)(Ah + aBase0), ah1 = *(const f16x8*)(Ah + aBase1);
    f16x8 al0 = *(const f16x8*)(Al + aBase0), al1 = *(const f16x8*)(Al + aBase1);
    f16x8 bh0 = *(const f16x8*)(Bh + bBase0), bh1 = *(const f16x8*)(Bh + bBase1);
    f16x8 bl0 = *(const f16x8*)(Bl + bBase0), bl1 = *(const f16x8*)(Bl + bBase1);
    for (int kt = 0; kt < NB; kt += 32) {
        f16x8 nah0, nah1, nal0, nal1, nbh0, nbh1, nbl0, nbl1;
        if (kt + 32 < NB) {
            size_t off = kt + 32;
            nah0 = *(const f16x8*)(Ah + aBase0 + off);
            nah1 = *(const f16x8*)(Ah + aBase1 + off);
            nal0 = *(const f16x8*)(Al + aBase0 + off);
            nal1 = *(const f16x8*)(Al + aBase1 + off);
            nbh0 = *(const f16x8*)(Bh + bBase0 + off);
            nbh1 = *(const f16x8*)(Bh + bBase1 + off);
            nbl0 = *(const f16x8*)(Bl + bBase0 + off);
            nbl1 = *(const f16x8*)(Bl + bBase1 + off);
        }
        f16x8 ahv[2] = {ah0, ah1}, alv[2] = {al0, al1};
        f16x8 bhv[2] = {bh0, bh1}, blv[2] = {bl0, bl1};
        #pragma unroll
        for (int mi = 0; mi < 2; ++mi)
            #pragma unroll
            for (int mj = 0; mj < 2; ++mj) {
                acc[mi][mj] = __builtin_amdgcn_mfma_f32_16x16x32_f16(alv[mi], blv[mj], acc[mi][mj], 0, 0, 0);
                acc[mi][mj] = __builtin_amdgcn_mfma_f32_16x16x32_f16(alv[mi], bhv[mj], acc[mi][mj], 0, 0, 0);
                acc[mi][mj] = __builtin_amdgcn_mfma_f32_16x16x32_f16(ahv[mi], blv[mj], acc[mi][mj], 0, 0, 0);
                acc[mi][mj] = __builtin_amdgcn_mfma_f32_16x16x32_f16(ahv[mi], bhv[mj], acc[mi][mj], 0, 0, 0);
            }
        ah0 = nah0; ah1 = nah1; al0 = nal0; al1 = nal1;
        bh0 = nbh0; bh1 = nbh1; bl0 = nbl0; bl1 = nbl1;
    }
    #pragma unroll
    for (int mi = 0; mi < 2; ++mi)
        #pragma unroll
        for (int mj = 0; mj < 2; ++mj)
            #pragma unroll
            for (int r = 0; r < 4; ++r) {
                int i = i0 + mi * 16 + kb * 4 + r;
                int j = j0 + mj * 16 + lr;
                float o = acc[mi][mj][r] + (bias ? bias[j] : 0.f);
                #pragma unroll
                for (int c = 0; c < NCOPY; ++c)
                    C[(size_t)c * copyStride + (size_t)i * NB + j] = o;
            }
}

// Generic 800x800 transpose: dst[j][e] = src[e][j].
__global__ __launch_bounds__(256) void transpose_kernel(
    const float* __restrict__ src, float* __restrict__ dst)
{
    __shared__ float T[32][33];
    int e0 = blockIdx.y * 32, j0 = blockIdx.x * 32;
    int tid = threadIdx.x;
    int r = tid >> 3, c4 = (tid & 7) * 4;
    float4 v = *(const float4*)(src + (size_t)(e0 + r) * NB + j0 + c4);
    T[r][c4 + 0] = v.x; T[r][c4 + 1] = v.y; T[r][c4 + 2] = v.z; T[r][c4 + 3] = v.w;
    __syncthreads();
    float4 o;
    o.x = T[c4 + 0][r]; o.y = T[c4 + 1][r]; o.z = T[c4 + 2][r]; o.w = T[c4 + 3][r];
    *(float4*)(dst + (size_t)(j0 + r) * NB + e0 + c4) = o;
}

// C[bz][i][j] = sum_k AT[bz][k][i] * BT[bz][k][j]  (k-major, 64x64, 4x4/thread).
template<int EPI>
__global__ __launch_bounds__(256) void gemm_kmaj64_kernel(
    const float* __restrict__ AT, const float* __restrict__ BT,
    float* __restrict__ C, int Kk,
    long aStride, long bStride, long cStride, int tilesX, int nBatch,
    const float* __restrict__ bias, int nCopies, long copyStride)
{
    int bid = blockIdx.x;
    int bz = bid % nBatch;
    int t_ = bid / nBatch;
    int i0 = (t_ / tilesX) * 64;
    int j0 = (t_ % tilesX) * 64;
    const float* Ab = AT + (size_t)bz * aStride;
    const float* Bb = BT + (size_t)bz * bStride;
    float* Cb = C + (size_t)bz * cStride;
    int tid = threadIdx.x;
    int tx = tid & 15, ty = tid >> 4;
    __shared__ __align__(16) float As[32][68];
    __shared__ __align__(16) float Bs[32][68];
    float acc[4][4] = {};
    for (int kt = 0; kt < Kk; kt += 32) {
        #pragma unroll
        for (int l = 0; l < 2; ++l) {
            int s = tid + l * 256;
            int k = s >> 4;
            int c4 = (s & 15) * 4;
            float4 va = make_float4(0.f, 0.f, 0.f, 0.f);
            if (i0 + c4 < NB) va = *(const float4*)(Ab + (size_t)(kt + k) * NB + i0 + c4);
            *(float4*)&As[k][c4] = va;
            float4 vb = make_float4(0.f, 0.f, 0.f, 0.f);
            if (j0 + c4 < NB) vb = *(const float4*)(Bb + (size_t)(kt + k) * NB + j0 + c4);
            *(float4*)&Bs[k][c4] = vb;
        }
        __syncthreads();
        #pragma unroll 8
        for (int kk = 0; kk < 32; ++kk) {
            float4 a4 = *(const float4*)&As[kk][ty * 4];
            float4 b4 = *(const float4*)&Bs[kk][tx * 4];
            acc[0][0] += a4.x * b4.x; acc[0][1] += a4.x * b4.y; acc[0][2] += a4.x * b4.z; acc[0][3] += a4.x * b4.w;
            acc[1][0] += a4.y * b4.x; acc[1][1] += a4.y * b4.y; acc[1][2] += a4.y * b4.z; acc[1][3] += a4.y * b4.w;
            acc[2][0] += a4.z * b4.x; acc[2][1] += a4.z * b4.y; acc[2][2] += a4.z * b4.z; acc[2][3] += a4.z * b4.w;
            acc[3][0] += a4.w * b4.x; acc[3][1] += a4.w * b4.y; acc[3][2] += a4.w * b4.z; acc[3][3] += a4.w * b4.w;
        }
        __syncthreads();
    }
    int j = j0 + tx * 4;
    if (j >= NB) return;
    #pragma unroll
    for (int m = 0; m < 4; ++m) {
        int i = i0 + ty * 4 + m;
        if (i >= NB) continue;
        float4 o;
        o.x = acc[m][0]; o.y = acc[m][1]; o.z = acc[m][2]; o.w = acc[m][3];
        *(float4*)(Cb + (size_t)i * NB + j) = o;
    }
}

// In-place antisymmetrization: M <- M - M^T per batch.
__global__ __launch_bounds__(256) void antisym_kernel(float* __restrict__ M, int nBatch)
{
    int bid = blockIdx.x;
    int b = bid % nBatch;
    int t_ = bid / nBatch;
    int ti = t_ / 25, tj = t_ % 25;
    if (ti > tj) return;
    float* Mb_ = M + (size_t)b * NN_;
    __shared__ float T1[32][33];
    __shared__ float T2[32][33];
    int tid = threadIdx.x;
    int r = tid >> 3, c4 = (tid & 7) * 4;
    int i0 = ti * 32, j0 = tj * 32;
    float4 x1 = *(const float4*)(Mb_ + (size_t)(i0 + r) * NB + j0 + c4);
    float4 x2 = *(const float4*)(Mb_ + (size_t)(j0 + r) * NB + i0 + c4);
    T1[r][c4] = x1.x; T1[r][c4 + 1] = x1.y; T1[r][c4 + 2] = x1.z; T1[r][c4 + 3] = x1.w;
    T2[r][c4] = x2.x; T2[r][c4 + 1] = x2.y; T2[r][c4 + 2] = x2.z; T2[r][c4 + 3] = x2.w;
    __syncthreads();
    float4 d1;
    d1.x = T1[r][c4 + 0] - T2[c4 + 0][r];
    d1.y = T1[r][c4 + 1] - T2[c4 + 1][r];
    d1.z = T1[r][c4 + 2] - T2[c4 + 2][r];
    d1.w = T1[r][c4 + 3] - T2[c4 + 3][r];
    *(float4*)(Mb_ + (size_t)(i0 + r) * NB + j0 + c4) = d1;
    if (ti != tj) {
        float4 d2;
        d2.x = T2[r][c4 + 0] - T1[c4 + 0][r];
        d2.y = T2[r][c4 + 1] - T1[c4 + 1][r];
        d2.z = T2[r][c4 + 2] - T1[c4 + 2][r];
        d2.w = T2[r][c4 + 3] - T1[c4 + 3][r];
        *(float4*)(Mb_ + (size_t)(j0 + r) * NB + i0 + c4) = d2;
    }
}

// Row top-K of D = S1 - S1^T: 4 rows/block, register-resident scan.
__global__ __launch_bounds__(256) void adj1_tile_kernel(
    const float* __restrict__ D, const float* __restrict__ alphaP,
    const float* __restrict__ noise, float* __restrict__ a1val, int* __restrict__ a1idx)
{
    int i0 = blockIdx.x * 4;
    int tid = threadIdx.x;
    __shared__ float sc[NB][5];
    __shared__ float vl[NB][5];
    __shared__ int selIdx[4][KSEL];
    float alpha = alphaP[0];
    if (tid < 200) {
        #pragma unroll
        for (int c = 0; c < 4; ++c) {
            int i = i0 + c;
            float4 d4 = *(const float4*)(D + (size_t)i * NB + tid * 4);
            float4 nz = *(const float4*)(noise + (size_t)i * NB + tid * 4);
            float4 th;
            th.x = tanhf(alpha * d4.x); th.y = tanhf(alpha * d4.y);
            th.z = tanhf(alpha * d4.z); th.w = tanhf(alpha * d4.w);
            th.x = th.x > 0.f ? th.x : 0.f;
            th.y = th.y > 0.f ? th.y : 0.f;
            th.z = th.z > 0.f ? th.z : 0.f;
            th.w = th.w > 0.f ? th.w : 0.f;
            int j = tid * 4;
            vl[j + 0][c] = th.x; vl[j + 1][c] = th.y; vl[j + 2][c] = th.z; vl[j + 3][c] = th.w;
            sc[j + 0][c] = score_f32(th.x, nz.x);
            sc[j + 1][c] = score_f32(th.y, nz.y);
            sc[j + 2][c] = score_f32(th.z, nz.z);
            sc[j + 3][c] = score_f32(th.w, nz.w);
        }
    }
    __syncthreads();
    int g = tid >> 6, l = tid & 63;
    float rv[13];
    #pragma unroll
    for (int k = 0; k < 13; ++k) {
        int i = l + k * 64;
        rv[k] = (i < NB) ? sc[i][g] : -3.0e30f;
    }
    REG_SCAN_13(rv, l, g, selIdx, ;)
    __syncthreads();
    if (tid < 4) {
        int tmp[KSEL];
        #pragma unroll
        for (int t = 0; t < KSEL; ++t) tmp[t] = selIdx[tid][t];
        for (int a = 1; a < KSEL; ++a) {
            int key = tmp[a]; int b = a - 1;
            while (b >= 0 && tmp[b] > key) { tmp[b + 1] = tmp[b]; --b; }
            tmp[b + 1] = key;
        }
        int i = i0 + tid;
        for (int t = 0; t < KSEL; ++t) {
            a1idx[i * KSEL + t] = tmp[t];
            a1val[i * KSEL + t] = vl[tmp[t]][tid];
        }
    }
}

// Column top-K of adj2, 4 columns/block, XCD-pinned, register-resident scan.
__global__ __launch_bounds__(256) void topk2_tile_kernel(
    const float* __restrict__ adj2, const float* __restrict__ noise,
    float* __restrict__ outp, int* __restrict__ sel2i, float* __restrict__ sel2v)
{
    int bid = blockIdx.x;
    int b = bid & 7;
    int j0 = (bid >> 3) * 4;
    int tid = threadIdx.x;
    const float* Ab = adj2 + (size_t)b * NN_;
    const float* Zb = noise + (size_t)b * NN_;
    float* Ob = outp + (size_t)b * NN_;
    __shared__ float sc[NB][5];
    __shared__ int selIdx[4][KSEL];
    float4 myval[4];
    #pragma unroll
    for (int k = 0; k < 4; ++k) {
        int i = tid + k * 256;
        if (i < NB) {
            float4 v  = *(const float4*)(Ab + (size_t)i * NB + j0);
            float4 nz = *(const float4*)(Zb + (size_t)i * NB + j0);
            myval[k] = v;
            sc[i][0] = score_f32(v.x, nz.x);
            sc[i][1] = score_f32(v.y, nz.y);
            sc[i][2] = score_f32(v.z, nz.z);
            sc[i][3] = score_f32(v.w, nz.w);
        }
    }
    __syncthreads();
    int g = tid >> 6, l = tid & 63;
    size_t lbase = ((size_t)b * NB + (j0 + g)) * KSEL;
    float rv[13];
    #pragma unroll
    for (int k = 0; k < 13; ++k) {
        int i = l + k * 64;
        rv[k] = (i < NB) ? sc[i][g] : -3.0e30f;
    }
    REG_SCAN_13(rv, l, g, selIdx, sel2i[lbase + t] = bi)
    if (l < KSEL) sc[selIdx[g][l]][g] = -1.0e30f;
    __syncthreads();
    #pragma unroll
    for (int k = 0; k < 4; ++k) {
        int i = tid + k * 256;
        if (i >= NB) continue;
        float vv[4] = {myval[k].x, myval[k].y, myval[k].z, myval[k].w};
        float o4[4];
        #pragma unroll
        for (int c = 0; c < 4; ++c) {
            bool seld = (sc[i][c] == -1.0e30f);
            o4[c] = seld ? vv[c] : 0.f;
            if (seld) {
                int rk = 0;
                for (int t = 0; t < KSEL; ++t) if (selIdx[c][t] == i) rk = t;
                sel2v[((size_t)b * NB + (j0 + c)) * KSEL + rk] = vv[c];
            }
        }
        *(float4*)(Ob + (size_t)i * NB + j0) = make_float4(o4[0], o4[1], o4[2], o4[3]);
    }
}

// Dense a3 values, row-streaming, XCD-pinned.
__global__ __launch_bounds__(256) void a3dense_kernel(
    const float* __restrict__ a2, const float* __restrict__ a1val,
    const int* __restrict__ a1idx, const float* __restrict__ alphaP,
    float* __restrict__ a3v)
{
    int bid = blockIdx.x;
    int b = bid & 7;
    int i = bid >> 3;
    int tid = threadIdx.x;
    __shared__ float sval[KSEL];
    __shared__ int   sidx[KSEL];
    if (tid < KSEL) { sval[tid] = a1val[i * KSEL + tid]; sidx[tid] = a1idx[i * KSEL + tid]; }
    __syncthreads();
    if (tid >= 200) return;
    float alpha = alphaP[0];
    const float* a2b = a2 + (size_t)b * NN_;
    int j = tid * 4;
    float4 acc = make_float4(0.f, 0.f, 0.f, 0.f);
    #pragma unroll
    for (int t = 0; t < KSEL; ++t) {
        float vt = sval[t];
        float4 s = *(const float4*)(a2b + (size_t)sidx[t] * NB + j);
        acc.x = fmaf(vt, s.x, acc.x);
        acc.y = fmaf(vt, s.y, acc.y);
        acc.z = fmaf(vt, s.z, acc.z);
        acc.w = fmaf(vt, s.w, acc.w);
    }
    float4 th;
    th.x = tanhf(alpha * acc.x); th.y = tanhf(alpha * acc.y);
    th.z = tanhf(alpha * acc.z); th.w = tanhf(alpha * acc.w);
    th.x = th.x > 0.f ? th.x : 0.f;
    th.y = th.y > 0.f ? th.y : 0.f;
    th.z = th.z > 0.f ? th.z : 0.f;
    th.w = th.w > 0.f ? th.w : 0.f;
    *(float4*)(a3v + (size_t)b * NN_ + (size_t)i * NB + j) = th;
}

// Column top-K of precomputed a3v, 4 columns/block, register-resident scan.
__global__ __launch_bounds__(256) void a3topk_tile_kernel(
    const float* __restrict__ a3v, const float* __restrict__ noise,
    int* __restrict__ sel3i, float* __restrict__ sel3v)
{
    int bid = blockIdx.x;
    int b = bid & 7;
    int j0 = (bid >> 3) * 4;
    int tid = threadIdx.x;
    const float* Ab = a3v + (size_t)b * NN_;
    const float* Zb = noise + (size_t)b * NN_;
    __shared__ float sc[NB][5];
    __shared__ int selIdx[4][KSEL];
    float4 myval[4];
    #pragma unroll
    for (int k = 0; k < 4; ++k) {
        int i = tid + k * 256;
        if (i < NB) {
            float4 v  = *(const float4*)(Ab + (size_t)i * NB + j0);
            float4 nz = *(const float4*)(Zb + (size_t)i * NB + j0);
            myval[k] = v;
            sc[i][0] = score_f32(v.x, nz.x);
            sc[i][1] = score_f32(v.y, nz.y);
            sc[i][2] = score_f32(v.z, nz.z);
            sc[i][3] = score_f32(v.w, nz.w);
        }
    }
    __syncthreads();
    int g = tid >> 6, l = tid & 63;
    size_t lbase = ((size_t)b * NB + (j0 + g)) * KSEL;
    float rv[13];
    #pragma unroll
    for (int k = 0; k < 13; ++k) {
        int i = l + k * 64;
        rv[k] = (i < NB) ? sc[i][g] : -3.0e30f;
    }
    REG_SCAN_13(rv, l, g, selIdx, sel3i[lbase + t] = bi)
    if (l < KSEL) sc[selIdx[g][l]][g] = -1.0e30f;
    __syncthreads();
    #pragma unroll
    for (int k = 0; k < 4; ++k) {
        int i = tid + k * 256;
        if (i >= NB) continue;
        float vv[4] = {myval[k].x, myval[k].y, myval[k].z, myval[k].w};
        #pragma unroll
        for (int c = 0; c < 4; ++c) {
            if (sc[i][c] == -1.0e30f) {
                int rk = 0;
                for (int t = 0; t < KSEL; ++t) if (selIdx[c][t] == i) rk = t;
                sel3v[((size_t)b * NB + (j0 + c)) * KSEL + rk] = vv[c];
            }
        }
    }
}

// Qn[i,:] = sum_t a1val[i,t]*Wqt[a1idx[i,t],:] + bq
__global__ __launch_bounds__(256) void qn_sparse_kernel(
    const float* __restrict__ a1v, const int* __restrict__ a1i,
    const float* __restrict__ Wqt, const float* __restrict__ bq,
    float* __restrict__ Qn)
{
    int i = blockIdx.x;
    int tid = threadIdx.x;
    __shared__ float sval[KSEL];
    __shared__ int   sidx[KSEL];
    if (tid < KSEL) { sval[tid] = a1v[i * KSEL + tid]; sidx[tid] = a1i[i * KSEL + tid]; }
    __syncthreads();
    for (int e = tid; e < NB; e += 256) {
        float acc = 0.f;
        #pragma unroll
        for (int t = 0; t < KSEL; ++t)
            acc = fmaf(sval[t], Wqt[(size_t)sidx[t] * NB + e], acc);
        Qn[(size_t)i * NB + e] = acc + bq[e];
    }
}

// scores[n,b] += a2val * g[n,j] over a2's selected entries
__global__ __launch_bounds__(256) void scatter_scores_kernel(
    const int* __restrict__ sel2i, const float* __restrict__ sel2v,
    const float* __restrict__ g, float* __restrict__ scores)
{
    int t = blockIdx.x * 256 + threadIdx.x;
    if (t >= NSEL) return;
    int j = (t / KSEL) % NB;
    int b = t / (KSEL * NB);
    int n = sel2i[t];
    float val = sel2v[t];
    atomicAdd(scores + (size_t)n * BB + b, val * g[(size_t)n * NB + j]);
}

// w[n,:] = softmax(scores[n,:]/sqrt(800))
__global__ __launch_bounds__(256) void softmax_w_kernel(
    const float* __restrict__ scores, float* __restrict__ w)
{
    int n = blockIdx.x * 256 + threadIdx.x;
    if (n >= NB) return;
    float s[BB];
    float mx = -INFINITY;
    for (int k = 0; k < BB; ++k) {
        s[k] = scores[(size_t)n * BB + k] / sqrtf(800.0f);
        if (s[k] > mx) mx = s[k];
    }
    float sum = 0.f;
    for (int k = 0; k < BB; ++k) { s[k] = expf(s[k] - mx); sum += s[k]; }
    for (int k = 0; k < BB; ++k) w[(size_t)n * BB + k] = s[k] / sum;
}

// u[n,j] += w[n,b] * a3val over a3's selected entries (row-major for MFMA A)
__global__ __launch_bounds__(256) void scatter_u_kernel(
    const int* __restrict__ sel3i, const float* __restrict__ sel3v,
    const float* __restrict__ w, float* __restrict__ u)
{
    int t = blockIdx.x * 256 + threadIdx.x;
    if (t >= NSEL) return;
    int j = (t / KSEL) % NB;
    int b = t / (KSEL * NB);
    int n = sel3i[t];
    float val = sel3v[t];
    atomicAdd(u + (size_t)n * NB + j, w[(size_t)n * BB + b] * val);
}

extern "C" void kernel_launch(void* const* d_in, const int* in_sizes, int n_in,
                              void* d_out, int out_size, void* d_ws, size_t ws_size,
                              hipStream_t stream)
{
    const float* tfeat      = (const float*)d_in[0];
    const float* dfeat      = (const float*)d_in[1];
    const float* alphaP     = (const float*)d_in[2];
    const float* emb1       = (const float*)d_in[3];
    const float* emb2       = (const float*)d_in[4];
    const float* lin1_w     = (const float*)d_in[5];
    const float* lin1_b     = (const float*)d_in[6];
    const float* lin2_w     = (const float*)d_in[7];
    const float* lin2_b     = (const float*)d_in[8];
    const float* in_proj_w  = (const float*)d_in[9];
    const float* in_proj_b  = (const float*)d_in[10];
    const float* out_proj_w = (const float*)d_in[11];
    const float* out_proj_b = (const float*)d_in[12];
    const float* noise1     = (const float*)d_in[13];
    const float* noise2     = (const float*)d_in[14];
    const float* noise3     = (const float*)d_in[15];
    float* out = (float*)d_out;

    const size_t NN  = NN_;               // 640000
    const size_t BNN = (size_t)BB * NN;   // 5120000

    float* ws  = (float*)d_ws;
    float* regA = ws;             // BNN f32: vh (16*NN f16); later u (f32)
    float* regB = regA + BNN;     // BNN f32: vl (16*NN f16); later g
    float* Mb  = regB + BNN;      // BNN f32: xnode hi/lo; M/adj2/a3v; Wqt + f16 pairs
    float* Qn  = Mb + BNN;        // NN  (S1 early, Qn later)
    float* Ob  = Qn + NN;         // NN  (n1T/n2T early, O later)
    float* a1v = Ob + NN;         // 16000
    int*   a1i = (int*)(a1v + NB * KSEL);       // 16000
    float* sel2v = (float*)(a1i + NB * KSEL);   // 128000
    int*   sel2i = (int*)(sel2v + NSEL);        // 128000
    float* sel3v = (float*)(sel2i + NSEL);      // 128000
    int*   sel3i = (int*)(sel3v + NSEL);        // 128000
    float* scores = (float*)(sel3i + NSEL);     // 6400
    float* wgt    = scores + NB * BB;           // 6400

    _Float16* vh = (_Float16*)regA;   // 16*NN f16
    _Float16* vl = (_Float16*)regB;   // 16*NN f16
    _Float16* xnh = (_Float16*)Mb;                 // 16*800*384 f16
    _Float16* xnl = xnh + (size_t)16 * NB * XK;    // 16*800*384 f16
    float* u   = regA;            // f32 after vh dead
    float* g   = regB;            // f32 after vl dead
    float* S1  = Qn;
    float* n1T = Ob;
    float* n2T = Ob + 64 * NB;
    float* a3v = Mb;              // adj2 dead after topk2
    float* Wqt = Mb;
    _Float16* f16b = (_Float16*)(Mb + NN);
    _Float16* Qh    = f16b;
    _Float16* Ql    = f16b + 1 * NN;
    _Float16* WkTh  = f16b + 2 * NN;
    _Float16* WkTl  = f16b + 3 * NN;
    _Float16* Wvh   = f16b + 4 * NN;
    _Float16* Wvl   = f16b + 5 * NN;
    _Float16* Wouth = f16b + 6 * NN;
    _Float16* Woutl = f16b + 7 * NN;
    _Float16* uh    = f16b + 8 * NN;
    _Float16* ul    = f16b + 9 * NN;
    _Float16* Oh    = f16b + 10 * NN;
    _Float16* Ol    = f16b + 11 * NN;
    float* OT = Ob;
    float* a2 = out;

    const float* bq = in_proj_b;
    const float* bv = in_proj_b + 2 * NB;
    const size_t XE = (size_t)BB * FF * NB * DD;

    // ---- adj1 path: S1 = n1 @ n2^T via k-major f32 gemm (bit-mimicking) ----
    lin_tanh_t_kernel<<<(NB * 64 + 255) / 256, 256, 0, stream>>>(emb1, lin1_w, lin1_b, alphaP, n1T);
    lin_tanh_t_kernel<<<(NB * 64 + 255) / 256, 256, 0, stream>>>(emb2, lin2_w, lin2_b, alphaP, n2T);
    gemm_kmaj64_kernel<0><<<13 * 13, 256, 0, stream>>>(n1T, n2T, S1, 64, 0, 0, 0, 13, 1, nullptr, 1, 0);
    antisym_kernel<<<25 * 25, 256, 0, stream>>>(S1, 1);
    adj1_tile_kernel<<<NB / 4, 256, 0, stream>>>(S1, alphaP, noise1, a1v, a1i);
    // ---- gram path: xnode f16 hi/lo -> triangular 32x32 MFMA gram (r25 best) ----
    xnode_kernel<<<(int)((XE + 255) / 256), 256, 0, stream>>>(tfeat, xnh, xnl);
    xnode_kernel<<<(int)((XE + 255) / 256), 256, 0, stream>>>(
        dfeat, xnh + (size_t)BB * NB * XK, xnl + (size_t)BB * NB * XK);
    gram_mfma_kernel<<<16 * 82, 256, 0, stream>>>(xnh, xnl, vh, vl);
    // ---- M = v1 @ v2^T via 64x64 split-f16 MFMA (xnode dead), antisym, topk2 ----
    mfma_m64_kernel<<<8 * 85, 128, 0, stream>>>(vh, vl, Mb);
    antisym_kernel<<<25 * 25 * BB, 256, 0, stream>>>(Mb, BB);
    topk2_tile_kernel<<<(NB / 4) * BB, 256, 0, stream>>>(Mb, noise2, a2, sel2i, sel2v);
    a3dense_kernel<<<NB * BB, 256, 0, stream>>>(a2, a1v, a1i, alphaP, a3v);
    a3topk_tile_kernel<<<(NB / 4) * BB, 256, 0, stream>>>(a3v, noise3, sel3i, sel3v);
    // ---- attention fold: all dense GEMMs via split-f16 MFMA ----
    transpose_kernel<<<dim3(25, 25), 256, 0, stream>>>(in_proj_w, Wqt);          // Wq^T f32
    qn_sparse_kernel<<<NB, 256, 0, stream>>>(a1v, a1i, Wqt, bq, Qn);
    split_kernel<<<(int)((NN + 255) / 256), 256, 0, stream>>>(Qn, Qh, Ql, (int)NN);
    transpose_split_kernel<<<dim3(25, 25), 256, 0, stream>>>(in_proj_w + NN, WkTh, WkTl);
    mfma_ab_kernel<1><<<157, 256, 0, stream>>>(Qh, Ql, WkTh, WkTl, g, nullptr, 0);
    hipMemsetAsync(scores, 0, NB * BB * sizeof(float), stream);
    scatter_scores_kernel<<<NSEL / 256, 256, 0, stream>>>(sel2i, sel2v, g, scores);
    softmax_w_kernel<<<(NB + 255) / 256, 256, 0, stream>>>(scores, wgt);
    hipMemsetAsync(u, 0, NN * sizeof(float), stream);
    scatter_u_kernel<<<NSEL / 256, 256, 0, stream>>>(sel3i, sel3v, wgt, u);
    split_kernel<<<(int)((NN + 255) / 256), 256, 0, stream>>>(u, uh, ul, (int)NN);
    split_kernel<<<(int)((NN + 255) / 256), 256, 0, stream>>>(in_proj_w + 2 * NN, Wvh, Wvl, (int)NN);
    mfma_ab_kernel<1><<<157, 256, 0, stream>>>(uh, ul, Wvh, Wvl, OT, bv, 0);
    split_kernel<<<(int)((NN + 255) / 256), 256, 0, stream>>>(OT, Oh, Ol, (int)NN);
    split_kernel<<<(int)((NN + 255) / 256), 256, 0, stream>>>(out_proj_w, Wouth, Woutl, (int)NN);
    mfma_ab_kernel<8><<<157, 256, 0, stream>>>(Oh, Ol, Wouth, Woutl, out, out_proj_b, (long)NN);
}